// Round 11
// baseline (198.123 us; speedup 1.0000x reference)
//
#include <hip/hip_runtime.h>
#include <math.h>

#define B_ 4
#define N_ 4096
#define K_ 16
#define NT 64                    // 64 tiles of 64 points per cloud
#define INF __builtin_huge_valf()
#define SLACK 1e-3f              // covers expanded-form fp error in bound test

__device__ __forceinline__ float dpp_shr1_f(float x) {
    return __int_as_float(__builtin_amdgcn_update_dpp(
        __float_as_int(x), __float_as_int(x), 0x111, 0xF, 0xF, false));
}
__device__ __forceinline__ int dpp_shr1_i(int x) {
    return __builtin_amdgcn_update_dpp(x, x, 0x111, 0xF, 0xF, false);
}
__device__ __forceinline__ float readlane_f(float x, int l) {
    return __int_as_float(__builtin_amdgcn_readlane(__float_as_int(x), l));
}
__device__ __forceinline__ float rflf(float x) {   // force to SGPR
    return __int_as_float(__builtin_amdgcn_readfirstlane(__float_as_int(x)));
}
#if __has_builtin(__builtin_amdgcn_inverse_ballot_w64)
#define LANEBIT(m, lane) __builtin_amdgcn_inverse_ballot_w64(m)
#else
#define LANEBIT(m, lane) ((((m) >> (lane)) & 1ull) != 0)
#endif

// pop ONE candidate from mask mi into sorted 16-list (lanes 0..15 asc)
#define POP1(mi, di, sdi, sii, tb)                                         \
    {   int src = __builtin_ctzll(mi); mi &= mi - 1;                       \
        float v = readlane_f(di, src);                                     \
        int  vi = (tb) + src;                                              \
        unsigned long long mg = __ballot(sdi > v);                         \
        float usd = dpp_shr1_f(sdi); int usi = dpp_shr1_i(sii);            \
        bool gt = LANEBIT(mg, lane);                                       \
        bool pg = LANEBIT(mg << 1, lane);                                  \
        sdi = gt ? (pg ? usd : v ) : sdi;                                  \
        sii = gt ? (pg ? usi : vi) : sii; }

__device__ __forceinline__ int spread4(int v) {    // 4 bits -> every 3rd pos
    return (v & 1) | ((v & 2) << 2) | ((v & 4) << 4) | ((v & 8) << 6);
}

__device__ __forceinline__ float aabb2f(float4 lo, float4 hi,
                                        float qx, float qy, float qz) {
    float dx = fmaxf(fmaxf(lo.x - qx, qx - hi.x), 0.f);
    float dy = fmaxf(fmaxf(lo.y - qy, qy - hi.y), 0.f);
    float dz = fmaxf(fmaxf(lo.z - qz, qz - hi.z), 0.f);
    return fmaf(dz, dz, fmaf(dy, dy, dx*dx));
}

// tile-order bitonic sort: MUST tie-break on tile id — AABB keys tie often
// (key 0 for every box containing the query); strict compare drops/dups tiles.
#define TILE_SORT(sk, st)                                                  \
    _Pragma("unroll")                                                      \
    for (int k = 2; k <= 64; k <<= 1) {                                    \
        _Pragma("unroll")                                                  \
        for (int jj = k >> 1; jj > 0; jj >>= 1) {                          \
            bool sel = ((lane & k) == 0) == ((lane & jj) == 0);            \
            float o = __shfl_xor(sk, jj); int a2 = __shfl_xor(st, jj);     \
            bool oless = (o < sk) || (o == sk && a2 < st);                 \
            if (oless == sel) { sk = o; st = a2; }                         \
        }                                                                  \
    }

// -- Morton counting-sort each (set,b) cloud: gs=(x,y,z,|p|^2), gidx=orig,
//    fused per-tile AABB computation (points kept in LDS) -------------------
__global__ __launch_bounds__(1024) void morton_sort_kernel(
    const float* __restrict__ ori, const float* __restrict__ adv,
    float4* __restrict__ gs, int* __restrict__ gidx, float4* __restrict__ ab)
{
    __shared__ int hist[4096];
    __shared__ int wpart[16];
    __shared__ float4 spt[N_];
    const int tid = threadIdx.x, lane = tid & 63, w = tid >> 6;
    const int set = blockIdx.x >> 2, b = blockIdx.x & 3;
    const float* src = (set ? adv : ori) + (size_t)b * (N_*3);
    float4* dst = gs + (size_t)blockIdx.x * N_;
    int*    dsi = gidx + (size_t)blockIdx.x * N_;
    float4* a   = ab + (size_t)blockIdx.x * (NT*2);

    #pragma unroll
    for (int k = 0; k < 4; ++k) hist[k*1024 + tid] = 0;
    __syncthreads();

    float px[4], py[4], pz[4]; int code[4];
    #pragma unroll
    for (int k = 0; k < 4; ++k) {
        int j = k*1024 + tid;
        float x = src[3*j+0], y = src[3*j+1], z = src[3*j+2];
        px[k] = x; py[k] = y; pz[k] = z;
        int ix = (int)((x + 4.25f) * (16.0f/8.5f));
        int iy = (int)((y + 4.25f) * (16.0f/8.5f));
        int iz = (int)((z + 4.25f) * (16.0f/8.5f));
        ix = ix < 0 ? 0 : (ix > 15 ? 15 : ix);
        iy = iy < 0 ? 0 : (iy > 15 ? 15 : iy);
        iz = iz < 0 ? 0 : (iz > 15 ? 15 : iz);
        code[k] = (spread4(ix) << 2) | (spread4(iy) << 1) | spread4(iz);
        atomicAdd(&hist[code[k]], 1);
    }
    __syncthreads();
    // prefix over 4096 buckets: thread owns hist[4t..4t+3]; wave-scan + 16-scan
    const int h0 = hist[4*tid], h1 = hist[4*tid+1],
              h2 = hist[4*tid+2], h3 = hist[4*tid+3];
    const int s = h0 + h1 + h2 + h3;
    int inc = s;
    #pragma unroll
    for (int d2 = 1; d2 < 64; d2 <<= 1) {
        int u = __shfl_up(inc, d2);
        if (lane >= d2) inc += u;
    }
    if (lane == 63) wpart[w] = inc;
    __syncthreads();
    if (w == 0) {
        int v = (lane < 16) ? wpart[lane] : 0;
        int iv = v;
        #pragma unroll
        for (int d2 = 1; d2 < 16; d2 <<= 1) {
            int u = __shfl_up(iv, d2);
            if (lane >= d2) iv += u;
        }
        if (lane < 16) wpart[lane] = iv - v;   // exclusive wave offsets
    }
    __syncthreads();
    int base = wpart[w] + inc - s;             // exclusive prefix, this thread
    hist[4*tid]   = base;
    hist[4*tid+1] = base + h0;
    hist[4*tid+2] = base + h0 + h1;
    hist[4*tid+3] = base + h0 + h1 + h2;
    __syncthreads();
    #pragma unroll
    for (int k = 0; k < 4; ++k) {
        int j = k*1024 + tid;
        int pos = atomicAdd(&hist[code[k]], 1);
        float pp = fmaf(pz[k],pz[k], fmaf(py[k],py[k], px[k]*px[k]));
        float4 f = make_float4(px[k], py[k], pz[k], pp);
        dst[pos] = f;
        spt[pos] = f;
        dsi[pos] = j;
    }
    __syncthreads();
    // fused per-tile AABBs from LDS
    #pragma unroll
    for (int i = 0; i < 4; ++i) {
        int t = w*4 + i;
        float4 p = spt[t*64 + lane];
        float x0=p.x, x1=p.x, y0=p.y, y1=p.y, z0=p.z, z1=p.z;
        #pragma unroll
        for (int s2 = 1; s2 < 64; s2 <<= 1) {
            x0 = fminf(x0, __shfl_xor(x0, s2)); x1 = fmaxf(x1, __shfl_xor(x1, s2));
            y0 = fminf(y0, __shfl_xor(y0, s2)); y1 = fmaxf(y1, __shfl_xor(y1, s2));
            z0 = fminf(z0, __shfl_xor(z0, s2)); z1 = fmaxf(z1, __shfl_xor(z1, s2));
        }
        if (lane == 0) {
            a[t*2+0] = make_float4(x0, y0, z0, 0.f);
            a[t*2+1] = make_float4(x1, y1, z1, 0.f);
        }
    }
}

// ------- fused kappa (+inline 1-NN argmin for adv), 1 query per wave --------
__global__ __launch_bounds__(256) void curv_kappa_kernel(
    const float4* __restrict__ gs, const int* __restrict__ gidx,
    const float4* __restrict__ ab, const float* __restrict__ nrm,
    double* __restrict__ acc)
{
    __shared__ double rs[4], rss[4];
    const int tid = threadIdx.x, lane = tid & 63, w = tid >> 6;
    const int gw  = blockIdx.x*4 + w;              // 0..32767
    const int job = gw >> 14;
    const int b   = (gw >> 12) & 3;
    const int sq  = gw & 4095;
    const float4* g  = gs + (size_t)(job*4+b) * N_;
    const int*    gi = gidx + (size_t)(job*4+b) * N_;
    const float4* abo = ab + (size_t)(job*4+b) * (NT*2);
    const float*  nb = nrm + (size_t)b * (N_*3);

    const int T0 = sq >> 6, sl = sq & 63;
    float4 f = g[sq];
    const float qx = rflf(f.x), qy = rflf(f.y), qz = rflf(f.z), qq = rflf(f.w);
    const float m2x = -2.f*qx, m2y = -2.f*qy, m2z = -2.f*qz;

    // ---- normal: own for ori; inline 1-NN over ori cloud for adv ----
    float nx, ny, nz;
    if (job == 0) {
        int n = __builtin_amdgcn_readfirstlane(gi[sq]);
        nx = rflf(nb[3*n+0]); ny = rflf(nb[3*n+1]); nz = rflf(nb[3*n+2]);
    } else {
        const float4* go  = gs + (size_t)b * N_;
        const int*    io  = gidx + (size_t)b * N_;
        const float4* abg = ab + (size_t)b * (NT*2);
        float4 lo = abg[lane*2+0], hi = abg[lane*2+1];
        float sk2 = aabb2f(lo, hi, qx, qy, qz); int st2 = lane;
        TILE_SORT(sk2, st2)
        float dm = INF; int jm = 0; float bnd = INF;
        for (int it = 0; it < NT; ++it) {
            float kd = readlane_f(sk2, it);
            if (kd >= bnd) break;
            int t = __builtin_amdgcn_readlane(st2, it);
            float4 p = go[t*64 + lane];
            float r = fmaf(p.z,m2z, fmaf(p.y,m2y, fmaf(p.x,m2x, p.w)));
            if (r < dm) { dm = r; jm = t*64 + lane; }
            float gm = dm;
            #pragma unroll
            for (int s2 = 1; s2 < 64; s2 <<= 1) gm = fminf(gm, __shfl_xor(gm, s2));
            bnd = gm + qq + SLACK;
        }
        #pragma unroll
        for (int s2 = 1; s2 < 64; s2 <<= 1) {      // lex (r, idx) min -> uniform
            float od = __shfl_xor(dm, s2); int oj = __shfl_xor(jm, s2);
            if (od < dm || (od == dm && oj < jm)) { dm = od; jm = oj; }
        }
        int nn = io[jm];
        nx = rflf(nb[3*nn+0]); ny = rflf(nb[3*nn+1]); nz = rflf(nb[3*nn+2]);
    }

    // ---- own-cloud tile order (per-query, tight) ----
    float4 lo = abo[lane*2+0], hi = abo[lane*2+1];
    float sk = aabb2f(lo, hi, qx, qy, qz); int st = lane;
    TILE_SORT(sk, st)

    // ---- seed: bitonic sort of own tile T0 ----
    const int j0 = T0*64 + lane;
    float sd; int si = j0;
    {
        float4 p = g[j0];
        sd = fmaf(p.z,m2z, fmaf(p.y,m2y, fmaf(p.x,m2x, p.w)));
        if (lane == sl) sd = INF;                  // exclude self
    }
    #pragma unroll
    for (int k = 2; k <= 64; k <<= 1) {
        #pragma unroll
        for (int jj = k >> 1; jj > 0; jj >>= 1) {
            bool sel = ((lane & k) == 0) == ((lane & jj) == 0);
            float o = __shfl_xor(sd, jj); int a2 = __shfl_xor(si, jj);
            if ((o < sd) == sel) { sd = o; si = a2; }
        }
    }
    float tau = readlane_f(sd, 15);

    // ---- sorted-order tile scan with per-query early exit ----
    for (int it = 0; it < NT; ++it) {
        float kd = readlane_f(sk, it);
        if (kd >= tau + qq + SLACK) break;
        int t = __builtin_amdgcn_readlane(st, it);
        if (t == T0) continue;
        int tb = t*64;
        float4 p = g[tb + lane];
        float d = fmaf(p.z,m2z, fmaf(p.y,m2y, fmaf(p.x,m2x, p.w)));
        unsigned long long m = __ballot(d < tau);
        if (m) {
            do { POP1(m, d, sd, si, tb) } while (m);
            tau = readlane_f(sd, 15);
        }
    }

    // ---- kappa = mean_k |dot(normalize(nn - q), normal)| ----
    float tl = 0.0f;
    if (lane < K_) {
        float4 p2 = g[si];
        float vx = p2.x - qx, vy = p2.y - qy, vz = p2.z - qz;
        float L  = sqrtf(vx*vx + vy*vy + vz*vz) + 1e-12f;
        tl = fabsf(fmaf(vz,nz, fmaf(vy,ny, vx*nx))) / L;
    }
    tl += __shfl_xor(tl, 1); tl += __shfl_xor(tl, 2);
    tl += __shfl_xor(tl, 4); tl += __shfl_xor(tl, 8);

    if (lane == 0) {
        double kap = (double)tl * (1.0/16.0);
        rs[w] = kap; rss[w] = kap*kap;
    }
    __syncthreads();
    if (tid == 0) {                                // block spans one (job,b)
        double s  = rs[0] + rs[1] + rs[2] + rs[3];
        double ss = rss[0] + rss[1] + rss[2] + rss[3];
        int row = job*4 + b;
        atomicAdd(&acc[row*2+0], s);
        atomicAdd(&acc[row*2+1], ss);
    }
}

__global__ void curv_finalize_kernel(const double* __restrict__ acc,
                                     float* __restrict__ out)
{
    if (threadIdx.x == 0 && blockIdx.x == 0) {
        double st[8];
        #pragma unroll
        for (int r = 0; r < 8; ++r) {
            double s   = acc[2*r+0];
            double ss  = acc[2*r+1];
            double var = (ss - s*s / (double)N_) / (double)(N_ - 1);
            st[r] = var > 0.0 ? sqrt(var) : 0.0;
        }
        double o = 0.0;
        #pragma unroll
        for (int bb = 0; bb < 4; ++bb) o += fabs(st[4+bb] - st[bb]);
        out[0] = (float)(o * 0.25);
    }
}

extern "C" void kernel_launch(void* const* d_in, const int* in_sizes, int n_in,
                              void* d_out, int out_size, void* d_ws, size_t ws_size,
                              hipStream_t stream)
{
    const float* ori = (const float*)d_in[0];
    const float* adv = (const float*)d_in[1];
    const float* nrm = (const float*)d_in[2];
    double* acc  = (double*)d_ws;                               // 256 B
    float4* gs   = (float4*)((char*)d_ws + 256);                // 512 KB
    int*    gidx = (int*)((char*)d_ws + 256 + 524288);          // 128 KB
    float4* ab   = (float4*)((char*)d_ws + 256 + 524288 + 131072); // 16 KB
    float*  out  = (float*)d_out;

    hipMemsetAsync(acc, 0, 16 * sizeof(double), stream);
    morton_sort_kernel<<<8, 1024, 0, stream>>>(ori, adv, gs, gidx, ab);
    curv_kappa_kernel<<<8192, 256, 0, stream>>>(gs, gidx, ab, nrm, acc);
    curv_finalize_kernel<<<1, 64, 0, stream>>>(acc, out);
}

// Round 12
// 188.222 us; speedup vs baseline: 1.0526x; 1.0526x over previous
//
#include <hip/hip_runtime.h>
#include <math.h>

#define B_ 4
#define N_ 4096
#define K_ 16
#define NT 64                    // 64 tiles of 64 points per cloud
#define QW 8                     // queries per wave (ILP for the pop chains)
#define INF __builtin_huge_valf()
#define SLACK 1e-3f              // covers expanded-form fp error in bound test

__device__ __forceinline__ float dpp_shr1_f(float x) {
    return __int_as_float(__builtin_amdgcn_update_dpp(
        __float_as_int(x), __float_as_int(x), 0x111, 0xF, 0xF, false));
}
__device__ __forceinline__ int dpp_shr1_i(int x) {
    return __builtin_amdgcn_update_dpp(x, x, 0x111, 0xF, 0xF, false);
}
__device__ __forceinline__ float readlane_f(float x, int l) {
    return __int_as_float(__builtin_amdgcn_readlane(__float_as_int(x), l));
}
__device__ __forceinline__ float rflf(float x) {   // force to SGPR
    return __int_as_float(__builtin_amdgcn_readfirstlane(__float_as_int(x)));
}
#if __has_builtin(__builtin_amdgcn_inverse_ballot_w64)
#define LANEBIT(m, lane) __builtin_amdgcn_inverse_ballot_w64(m)
#else
#define LANEBIT(m, lane) ((((m) >> (lane)) & 1ull) != 0)
#endif

// pop ONE candidate from mask mi into sorted 16-list (lanes 0..15 asc)
#define POP1(mi, di, sdi, sii, tb)                                         \
    {   int src = __builtin_ctzll(mi); mi &= mi - 1;                       \
        float v = readlane_f(di, src);                                     \
        int  vi = (tb) + src;                                              \
        unsigned long long mg = __ballot(sdi > v);                         \
        float usd = dpp_shr1_f(sdi); int usi = dpp_shr1_i(sii);            \
        bool gt = LANEBIT(mg, lane);                                       \
        bool pg = LANEBIT(mg << 1, lane);                                  \
        sdi = gt ? (pg ? usd : v ) : sdi;                                  \
        sii = gt ? (pg ? usi : vi) : sii; }

__device__ __forceinline__ int spread4(int v) {    // 4 bits -> every 3rd pos
    return (v & 1) | ((v & 2) << 2) | ((v & 4) << 4) | ((v & 8) << 6);
}

__device__ __forceinline__ float aabb2f(float4 lo, float4 hi,
                                        float qx, float qy, float qz) {
    float dx = fmaxf(fmaxf(lo.x - qx, qx - hi.x), 0.f);
    float dy = fmaxf(fmaxf(lo.y - qy, qy - hi.y), 0.f);
    float dz = fmaxf(fmaxf(lo.z - qz, qz - hi.z), 0.f);
    return fmaf(dz, dz, fmaf(dy, dy, dx*dx));
}

// tile-order bitonic sort: MUST tie-break on tile id — AABB keys tie often.
#define TILE_SORT(sk, st)                                                  \
    _Pragma("unroll")                                                      \
    for (int k = 2; k <= 64; k <<= 1) {                                    \
        _Pragma("unroll")                                                  \
        for (int jj = k >> 1; jj > 0; jj >>= 1) {                          \
            bool sel = ((lane & k) == 0) == ((lane & jj) == 0);            \
            float o = __shfl_xor(sk, jj); int a2 = __shfl_xor(st, jj);     \
            bool oless = (o < sk) || (o == sk && a2 < st);                 \
            if (oless == sel) { sk = o; st = a2; }                         \
        }                                                                  \
    }

// -- Morton counting-sort each (set,b) cloud: gs=(x,y,z,|p|^2), gidx=orig,
//    fused per-tile AABB computation (points kept in LDS) -------------------
__global__ __launch_bounds__(1024) void morton_sort_kernel(
    const float* __restrict__ ori, const float* __restrict__ adv,
    float4* __restrict__ gs, int* __restrict__ gidx, float4* __restrict__ ab)
{
    __shared__ int hist[4096];
    __shared__ int wpart[16];
    __shared__ float4 spt[N_];
    const int tid = threadIdx.x, lane = tid & 63, w = tid >> 6;
    const int set = blockIdx.x >> 2, b = blockIdx.x & 3;
    const float* src = (set ? adv : ori) + (size_t)b * (N_*3);
    float4* dst = gs + (size_t)blockIdx.x * N_;
    int*    dsi = gidx + (size_t)blockIdx.x * N_;
    float4* a   = ab + (size_t)blockIdx.x * (NT*2);

    #pragma unroll
    for (int k = 0; k < 4; ++k) hist[k*1024 + tid] = 0;
    __syncthreads();

    float px[4], py[4], pz[4]; int code[4];
    #pragma unroll
    for (int k = 0; k < 4; ++k) {
        int j = k*1024 + tid;
        float x = src[3*j+0], y = src[3*j+1], z = src[3*j+2];
        px[k] = x; py[k] = y; pz[k] = z;
        int ix = (int)((x + 4.25f) * (16.0f/8.5f));
        int iy = (int)((y + 4.25f) * (16.0f/8.5f));
        int iz = (int)((z + 4.25f) * (16.0f/8.5f));
        ix = ix < 0 ? 0 : (ix > 15 ? 15 : ix);
        iy = iy < 0 ? 0 : (iy > 15 ? 15 : iy);
        iz = iz < 0 ? 0 : (iz > 15 ? 15 : iz);
        code[k] = (spread4(ix) << 2) | (spread4(iy) << 1) | spread4(iz);
        atomicAdd(&hist[code[k]], 1);
    }
    __syncthreads();
    // prefix over 4096 buckets: thread owns hist[4t..4t+3]; wave-scan + 16-scan
    const int h0 = hist[4*tid], h1 = hist[4*tid+1],
              h2 = hist[4*tid+2], h3 = hist[4*tid+3];
    const int s = h0 + h1 + h2 + h3;
    int inc = s;
    #pragma unroll
    for (int d2 = 1; d2 < 64; d2 <<= 1) {
        int u = __shfl_up(inc, d2);
        if (lane >= d2) inc += u;
    }
    if (lane == 63) wpart[w] = inc;
    __syncthreads();
    if (w == 0) {
        int v = (lane < 16) ? wpart[lane] : 0;
        int iv = v;
        #pragma unroll
        for (int d2 = 1; d2 < 16; d2 <<= 1) {
            int u = __shfl_up(iv, d2);
            if (lane >= d2) iv += u;
        }
        if (lane < 16) wpart[lane] = iv - v;   // exclusive wave offsets
    }
    __syncthreads();
    int base = wpart[w] + inc - s;             // exclusive prefix, this thread
    hist[4*tid]   = base;
    hist[4*tid+1] = base + h0;
    hist[4*tid+2] = base + h0 + h1;
    hist[4*tid+3] = base + h0 + h1 + h2;
    __syncthreads();
    #pragma unroll
    for (int k = 0; k < 4; ++k) {
        int j = k*1024 + tid;
        int pos = atomicAdd(&hist[code[k]], 1);
        float pp = fmaf(pz[k],pz[k], fmaf(py[k],py[k], px[k]*px[k]));
        float4 f = make_float4(px[k], py[k], pz[k], pp);
        dst[pos] = f;
        spt[pos] = f;
        dsi[pos] = j;
    }
    __syncthreads();
    // fused per-tile AABBs from LDS
    #pragma unroll
    for (int i = 0; i < 4; ++i) {
        int t = w*4 + i;
        float4 p = spt[t*64 + lane];
        float x0=p.x, x1=p.x, y0=p.y, y1=p.y, z0=p.z, z1=p.z;
        #pragma unroll
        for (int s2 = 1; s2 < 64; s2 <<= 1) {
            x0 = fminf(x0, __shfl_xor(x0, s2)); x1 = fmaxf(x1, __shfl_xor(x1, s2));
            y0 = fminf(y0, __shfl_xor(y0, s2)); y1 = fmaxf(y1, __shfl_xor(y1, s2));
            z0 = fminf(z0, __shfl_xor(z0, s2)); z1 = fmaxf(z1, __shfl_xor(z1, s2));
        }
        if (lane == 0) {
            a[t*2+0] = make_float4(x0, y0, z0, 0.f);
            a[t*2+1] = make_float4(x1, y1, z1, 0.f);
        }
    }
}

// ---- fused kappa (+inline 8-query 1-NN for adv), 8 queries per wave --------
__global__ __launch_bounds__(256) void curv_kappa_kernel(
    const float4* __restrict__ gs, const int* __restrict__ gidx,
    const float4* __restrict__ ab, const float* __restrict__ nrm,
    double* __restrict__ acc)
{
    __shared__ double rs[4], rss[4];
    const int tid = threadIdx.x, lane = tid & 63, w = tid >> 6;
    const int gw  = blockIdx.x*4 + w;              // 0..4095
    const int job = gw >> 11;
    const int b   = (gw >> 9) & 3;
    const int sq0 = (gw & 511) * QW;               // 8 Morton-adjacent queries
    const float4* g   = gs + (size_t)(job*4+b) * N_;
    const int*    gi  = gidx + (size_t)(job*4+b) * N_;
    const float4* abo = ab + (size_t)(job*4+b) * (NT*2);
    const float*  nb  = nrm + (size_t)b * (N_*3);

    const int T0 = sq0 >> 6, sl = sq0 & 63;        // all 8 share seed tile

    float qxv[QW], qyv[QW], qzv[QW], qqv[QW], m2x[QW], m2y[QW], m2z[QW];
    #pragma unroll
    for (int i = 0; i < QW; ++i) {
        float4 fi = g[sq0+i];
        qxv[i] = rflf(fi.x); qyv[i] = rflf(fi.y);
        qzv[i] = rflf(fi.z); qqv[i] = rflf(fi.w);
        m2x[i] = -2.f*qxv[i]; m2y[i] = -2.f*qyv[i]; m2z[i] = -2.f*qzv[i];
    }

    // ---- normals: own index for ori; inline 8-query 1-NN over ori for adv --
    int nnv[QW];
    if (job == 0) {
        #pragma unroll
        for (int i = 0; i < QW; ++i) nnv[i] = gi[sq0+i];
    } else {
        const float4* go  = gs + (size_t)b * N_;
        const int*    io  = gidx + (size_t)b * N_;
        const float4* abg = ab + (size_t)b * (NT*2);
        float4 lo = abg[lane*2+0], hi = abg[lane*2+1];
        float sk = INF;
        #pragma unroll
        for (int i = 0; i < QW; ++i)
            sk = fminf(sk, aabb2f(lo, hi, qxv[i], qyv[i], qzv[i]));
        int st = lane;
        TILE_SORT(sk, st)
        float dm[QW]; int jm[QW];
        #pragma unroll
        for (int i = 0; i < QW; ++i) { dm[i] = INF; jm[i] = 0; }
        float bnd = INF;
        for (int it = 0; it < NT; ++it) {
            float kd = readlane_f(sk, it);
            if (kd >= bnd) break;
            int t = __builtin_amdgcn_readlane(st, it);
            float4 p = go[t*64 + lane];
            #pragma unroll
            for (int i = 0; i < QW; ++i) {
                float r = fmaf(p.z,m2z[i], fmaf(p.y,m2y[i], fmaf(p.x,m2x[i], p.w)));
                if (r < dm[i]) { dm[i] = r; jm[i] = t*64 + lane; }
            }
            float bmx = -INF;
            #pragma unroll
            for (int i = 0; i < QW; ++i) {
                float gm = dm[i];
                #pragma unroll
                for (int s2 = 1; s2 < 64; s2 <<= 1) gm = fminf(gm, __shfl_xor(gm, s2));
                bmx = fmaxf(bmx, gm + qqv[i]);
            }
            bnd = bmx + SLACK;
        }
        #pragma unroll
        for (int i = 0; i < QW; ++i) {             // lex (r, idx) min -> uniform
            float dmv = dm[i]; int jmv = jm[i];
            #pragma unroll
            for (int s2 = 1; s2 < 64; s2 <<= 1) {
                float od = __shfl_xor(dmv, s2); int oj = __shfl_xor(jmv, s2);
                if (od < dmv || (od == dmv && oj < jmv)) { dmv = od; jmv = oj; }
            }
            nnv[i] = io[jmv];
        }
    }

    // ---- own-cloud tile order ----
    float sk, skq; int st;
    {
        float4 lo = abo[lane*2+0], hi = abo[lane*2+1];
        skq = INF;
        #pragma unroll
        for (int i = 0; i < QW; ++i)
            skq = fminf(skq, aabb2f(lo, hi, qxv[i], qyv[i], qzv[i]));
        sk = skq; st = lane;
        TILE_SORT(sk, st)
    }

    // ---- seed: bitonic sort of own tile T0, 8 interleaved chains ----
    float sd[QW]; int si[QW];
    {
        float4 p = g[T0*64 + lane];
        #pragma unroll
        for (int i = 0; i < QW; ++i) {
            sd[i] = fmaf(p.z,m2z[i], fmaf(p.y,m2y[i], fmaf(p.x,m2x[i], p.w)));
            si[i] = T0*64 + lane;
            if (lane == sl + i) sd[i] = INF;       // exclude self
        }
    }
    #pragma unroll
    for (int k = 2; k <= 64; k <<= 1) {
        #pragma unroll
        for (int jj = k >> 1; jj > 0; jj >>= 1) {
            bool sel = ((lane & k) == 0) == ((lane & jj) == 0);
            #pragma unroll
            for (int i = 0; i < QW; ++i) {
                float o = __shfl_xor(sd[i], jj); int a2 = __shfl_xor(si[i], jj);
                if ((o < sd[i]) == sel) { sd[i] = o; si[i] = a2; }
            }
        }
    }
    float tauv[QW];
    #pragma unroll
    for (int i = 0; i < QW; ++i) tauv[i] = readlane_f(sd[i], 15);
    float bound;
    {
        float bmx = -INF;
        #pragma unroll
        for (int i = 0; i < QW; ++i) bmx = fmaxf(bmx, tauv[i] + qqv[i]);
        bound = bmx + SLACK;
    }

    // ---- sorted-order tile scan, early exit, 8-way interleaved pops ----
    for (int it = 0; it < NT; ++it) {
        float kd = readlane_f(sk, it);
        if (kd >= bound) break;
        int t = __builtin_amdgcn_readlane(st, it);
        if (t == T0) continue;
        int tb = t*64;
        float4 p = g[tb + lane];
        float dd[QW]; unsigned long long mm[QW];
        #pragma unroll
        for (int i = 0; i < QW; ++i) {
            dd[i] = fmaf(p.z,m2z[i], fmaf(p.y,m2y[i], fmaf(p.x,m2x[i], p.w)));
            mm[i] = __ballot(dd[i] < tauv[i]);
        }
        unsigned long long anym = 0;
        #pragma unroll
        for (int i = 0; i < QW; ++i) anym |= mm[i];
        if (anym) {
            for (;;) {
                unsigned long long am = 0;
                #pragma unroll
                for (int i = 0; i < QW; ++i) am |= mm[i];
                if (!am) break;
                #pragma unroll
                for (int i = 0; i < QW; ++i)
                    if (mm[i]) POP1(mm[i], dd[i], sd[i], si[i], tb)
            }
            float bmx = -INF;
            #pragma unroll
            for (int i = 0; i < QW; ++i) {
                tauv[i] = readlane_f(sd[i], 15);
                bmx = fmaxf(bmx, tauv[i] + qqv[i]);
            }
            bound = bmx + SLACK;
        }
    }

    // ---- kappa = mean_k |dot(normalize(nn - q), normal)| ----
    double ksum = 0.0, kss = 0.0;
    #pragma unroll
    for (int i = 0; i < QW; ++i) {
        float nx = rflf(nb[3*nnv[i]+0]);
        float ny = rflf(nb[3*nnv[i]+1]);
        float nz = rflf(nb[3*nnv[i]+2]);
        float tl = 0.0f;
        if (lane < K_) {
            float4 p2 = g[si[i]];
            float vx = p2.x - qxv[i], vy = p2.y - qyv[i], vz = p2.z - qzv[i];
            float L  = sqrtf(vx*vx + vy*vy + vz*vz) + 1e-12f;
            tl = fabsf(fmaf(vz,nz, fmaf(vy,ny, vx*nx))) / L;
        }
        tl += __shfl_xor(tl, 1); tl += __shfl_xor(tl, 2);
        tl += __shfl_xor(tl, 4); tl += __shfl_xor(tl, 8);
        if (lane == 0) {
            double kap = (double)tl * (1.0/16.0);
            ksum += kap; kss += kap*kap;
        }
    }

    if (lane == 0) { rs[w] = ksum; rss[w] = kss; }
    __syncthreads();
    if (tid == 0) {                                // block spans one (job,b)
        double s  = rs[0] + rs[1] + rs[2] + rs[3];
        double ss = rss[0] + rss[1] + rss[2] + rss[3];
        int row = job*4 + b;
        atomicAdd(&acc[row*2+0], s);
        atomicAdd(&acc[row*2+1], ss);
    }
}

__global__ void curv_finalize_kernel(const double* __restrict__ acc,
                                     float* __restrict__ out)
{
    if (threadIdx.x == 0 && blockIdx.x == 0) {
        double st[8];
        #pragma unroll
        for (int r = 0; r < 8; ++r) {
            double s   = acc[2*r+0];
            double ss  = acc[2*r+1];
            double var = (ss - s*s / (double)N_) / (double)(N_ - 1);
            st[r] = var > 0.0 ? sqrt(var) : 0.0;
        }
        double o = 0.0;
        #pragma unroll
        for (int bb = 0; bb < 4; ++bb) o += fabs(st[4+bb] - st[bb]);
        out[0] = (float)(o * 0.25);
    }
}

extern "C" void kernel_launch(void* const* d_in, const int* in_sizes, int n_in,
                              void* d_out, int out_size, void* d_ws, size_t ws_size,
                              hipStream_t stream)
{
    const float* ori = (const float*)d_in[0];
    const float* adv = (const float*)d_in[1];
    const float* nrm = (const float*)d_in[2];
    double* acc  = (double*)d_ws;                               // 256 B
    float4* gs   = (float4*)((char*)d_ws + 256);                // 512 KB
    int*    gidx = (int*)((char*)d_ws + 256 + 524288);          // 128 KB
    float4* ab   = (float4*)((char*)d_ws + 256 + 524288 + 131072); // 16 KB
    float*  out  = (float*)d_out;

    hipMemsetAsync(acc, 0, 16 * sizeof(double), stream);
    morton_sort_kernel<<<8, 1024, 0, stream>>>(ori, adv, gs, gidx, ab);
    curv_kappa_kernel<<<1024, 256, 0, stream>>>(gs, gidx, ab, nrm, acc);
    curv_finalize_kernel<<<1, 64, 0, stream>>>(acc, out);
}